// Round 2
// baseline (469.959 us; speedup 1.0000x reference)
//
#include <hip/hip_runtime.h>

typedef float vf4 __attribute__((ext_vector_type(4)));

// ======================================================================
// Compile-time CG table: identical algorithm to the round-1 setup kernel
// (which passed validation), evaluated by the C++ constexpr interpreter
// in fp64. Coefficients become instruction literals; exact zeros fold out.
// ======================================================================
namespace cgc {

struct FTab { double f[13]; };
constexpr FTab mkft(){ FTab t{}; t.f[0]=1.0; for(int i=1;i<13;i++) t.f[i]=t.f[i-1]*i; return t; }
constexpr FTab FTB = mkft();

constexpr double csqrt(double x){
  double g = x < 1.0 ? 1.0 : x;
  for(int i=0;i<40;i++) g = 0.5*(g + x/g);
  return g;
}

constexpr double cgcoef(int j1,int m1,int j2,int m2,int j3,int m3){
  if (m1+m2 != m3) return 0.0;
  double pref = csqrt((double)(2*j3+1) * FTB.f[j3+j1-j2] * FTB.f[j3-j1+j2]
                      * FTB.f[j1+j2-j3] / FTB.f[j1+j2+j3+1]);
  pref *= csqrt(FTB.f[j3+m3]*FTB.f[j3-m3]*FTB.f[j1-m1]*FTB.f[j1+m1]
                *FTB.f[j2-m2]*FTB.f[j2+m2]);
  double s = 0.0;
  for(int k=0;k<=j1+j2-j3;k++){
    int e1=j1+j2-j3-k, e2=j1-m1-k, e3=j2+m2-k, e4=j3-j2+m1+k, e5=j3-j1-m2+k;
    if (e1<0||e2<0||e3<0||e4<0||e5<0) continue;
    double prod = FTB.f[k]*FTB.f[e1]*FTB.f[e2]*FTB.f[e3]*FTB.f[e4]*FTB.f[e5];
    s += (k&1) ? (-1.0/prod) : (1.0/prod);
  }
  return pref*s;
}

struct Tab { double v[11][125]; };

constexpr Tab build(){
  Tab T{};
  constexpr int PL1[11]={0,0,0,1,1,1,1,2,2,2,2};
  constexpr int PL2[11]={0,1,2,0,1,1,2,0,1,2,2};
  constexpr int PL3[11]={0,1,2,1,0,2,1,2,1,0,2};
  constexpr int NOUT[3]={3,4,4};
  // q matrices (real->complex change of basis), exactly as the validated kernel
  double qr[3][5][5]{}, qi[3][5][5]{};
  for(int l=0;l<3;l++){
    const double is2 = 0.70710678118654752440;
    for(int m=-l;m<0;m++){ qr[l][l+m][l-m]=is2; qi[l][l+m][l+m]=-is2; }
    qr[l][l][l]=1.0;
    for(int m=1;m<=l;m++){ double sg=(m&1)?-1.0:1.0; qr[l][l+m][l+m]=sg*is2; qi[l][l+m][l-m]=sg*is2; }
    if (l==1){ for(int a=0;a<5;a++)for(int b=0;b<5;b++){ double re=qr[1][a][b], im=qi[1][a][b]; qr[1][a][b]=im; qi[1][a][b]=-re; } }
    if (l==2){ for(int a=0;a<5;a++)for(int b=0;b<5;b++){ qr[2][a][b]=-qr[2][a][b]; qi[2][a][b]=-qi[2][a][b]; } }
  }
  for(int p=0;p<11;p++){
    int l1=PL1[p], l2=PL2[p], l3=PL3[p];
    int d1=2*l1+1, d2=2*l2+1, d3=2*l3+1;
    double cs[125]{};
    for(int i=0;i<d1;i++)for(int k=0;k<d2;k++)for(int m=0;m<d3;m++)
      cs[(i*d2+k)*d3+m] = cgcoef(l1,i-l1,l2,k-l2,l3,m-l3);
    double nrm2 = 0.0;
    for(int j=0;j<d1;j++)for(int lc=0;lc<d2;lc++)for(int n=0;n<d3;n++){
      double ar = 0.0;
      for(int i=0;i<d1;i++){
        double q1r=qr[l1][i][j], q1i=qi[l1][i][j];
        if (q1r==0.0 && q1i==0.0) continue;
        for(int k=0;k<d2;k++){
          double q2r=qr[l2][k][lc], q2i=qi[l2][k][lc];
          if (q2r==0.0 && q2i==0.0) continue;
          double abr=q1r*q2r-q1i*q2i, abi=q1r*q2i+q1i*q2r;
          for(int m=0;m<d3;m++){
            double c=cs[(i*d2+k)*d3+m];
            if (c==0.0) continue;
            double q3r=qr[l3][m][n], q3i=-qi[l3][m][n];   // conj(q3)
            ar += (abr*q3r - abi*q3i)*c;
          }
        }
      }
      T.v[p][(j*d2+lc)*d3+n] = ar;
      nrm2 += ar*ar;
    }
    double sc = csqrt((double)(2*l3+1)/(double)NOUT[l3]) / csqrt(nrm2);
    for(int e=0;e<d1*d2*d3;e++) T.v[p][e] *= sc;
  }
  return T;
}

constexpr Tab CGT = build();

} // namespace cgc

// ======================================================================
// Sparse per-path TP: unrolled loops, coefficients folded to literals,
// zero entries dead-code-eliminated.
// ======================================================================
template<int P,int L1,int L2,int L3>
__device__ __forceinline__ void tp_path(float wp, const float (&xi)[9],
                                        const float (&yi)[9], float (&o)[9])
{
  constexpr int D1=2*L1+1, D2=2*L2+1, D3=2*L3+1, O1=L1*L1, O2=L2*L2, O3=L3*L3;
  float z[D3];
#pragma unroll
  for(int k=0;k<D3;k++) z[k]=0.f;
#pragma unroll
  for(int i=0;i<D1;i++){
#pragma unroll
    for(int j=0;j<D2;j++){
      const float tt = xi[O1+i]*yi[O2+j];   // DCE'd if all k-coeffs are 0
#pragma unroll
      for(int k=0;k<D3;k++){
        const double cv = cgc::CGT.v[P][(i*D2+j)*D3+k];   // folds to constant
        if (cv > 1e-12 || cv < -1e-12)
          z[k] = fmaf((float)cv, tt, z[k]);
      }
    }
  }
#pragma unroll
  for(int k=0;k<D3;k++) o[O3+k] = fmaf(wp, z[k], o[O3+k]);
}

// ======================================================================
// Main fused kernel. Block = 64 b x 16 c (half the channels) so the W
// LDS tile is 24 KB -> 5+ blocks/CU. 256 threads = 16 c x 16 g, R=4.
// ======================================================================
__global__ __launch_bounds__(256, 5) void e3_tp_kernel(
    const float* __restrict__ x, const float* __restrict__ y,
    const float* __restrict__ dist, const float* __restrict__ Wl,
    const float* __restrict__ bias, float* __restrict__ out)
{
  __shared__ vf4 Ws4[32*16*3];           // W as [f=32][c=16][12] floats, 24 KB
  float* Ws = (float*)Ws4;
  const int t = threadIdx.x;
  const int bx = blockIdx.x;
  const int cbase = (bx & 1) * 16;
  const long bblk = (long)(bx >> 1) * 64;

  { // stage W_lin[32][352] slice (16 channels) -> LDS [f][cc][12]
#pragma unroll
    for (int idx = t; idx < 32*16*11; idx += 256) {
      const int f  = idx / 176;
      const int rm = idx - f*176;
      const int cc = rm / 11;
      const int p  = rm - cc*11;
      Ws[f*192 + cc*12 + p] = Wl[f*352 + (cbase+cc)*11 + p];
    }
  }
  __syncthreads();

  const int c = t & 15, g = t >> 4;
  const int ch = cbase + c;
  const long b0 = bblk + g*4;

  // ---- fused linear: w[r][p] = bias[ch][p] + sum_f dist[b0+r][f]*W[f][ch][p]
  float w[4][11];
#pragma unroll
  for (int p = 0; p < 11; p++){
    const float bb = bias[ch*11 + p];
#pragma unroll
    for (int r = 0; r < 4; r++) w[r][p] = bb;
  }

  const float* db = dist + b0*32;
  const vf4* wsrow = Ws4 + c*3;
#pragma unroll 1
  for (int fq = 0; fq < 8; fq++){
    vf4 dd[4];
#pragma unroll
    for (int r = 0; r < 4; r++) dd[r] = *(const vf4*)(db + r*32 + fq*4);
#pragma unroll
    for (int ff = 0; ff < 4; ff++){
      const vf4* wr = wsrow + (fq*4 + ff)*48;     // per-f stride = 48 vf4
      vf4 wa = wr[0], wb2 = wr[1], wc2 = wr[2];   // 3x ds_read_b128
      const float wl[11] = {wa.x,wa.y,wa.z,wa.w, wb2.x,wb2.y,wb2.z,wb2.w, wc2.x,wc2.y,wc2.z};
#pragma unroll
      for (int r = 0; r < 4; r++){
        const float dv = (ff==0) ? dd[r].x : (ff==1) ? dd[r].y : (ff==2) ? dd[r].z : dd[r].w;
#pragma unroll
        for (int p = 0; p < 11; p++) w[r][p] = fmaf(dv, wl[p], w[r][p]);
      }
    }
  }

  // ---- per-item tensor product ----
  const long ib = b0*32 + ch;
  const float* xp = x + ib*9;
  const float* yp = y + ib*9;
  float* op = out + ib*9;

#pragma unroll
  for (int r = 0; r < 4; r++){
    const float* xr = xp + r*288;   // next b: +32*9 floats
    const float* yr = yp + r*288;
    float xi[9], yi[9], o[9];
    { vf4 a_, b_; __builtin_memcpy(&a_, xr, 16); __builtin_memcpy(&b_, xr+4, 16);
      xi[0]=a_.x; xi[1]=a_.y; xi[2]=a_.z; xi[3]=a_.w;
      xi[4]=b_.x; xi[5]=b_.y; xi[6]=b_.z; xi[7]=b_.w; xi[8]=xr[8]; }
    { vf4 a_, b_; __builtin_memcpy(&a_, yr, 16); __builtin_memcpy(&b_, yr+4, 16);
      yi[0]=a_.x; yi[1]=a_.y; yi[2]=a_.z; yi[3]=a_.w;
      yi[4]=b_.x; yi[5]=b_.y; yi[6]=b_.z; yi[7]=b_.w; yi[8]=yr[8]; }
#pragma unroll
    for (int k = 0; k < 9; k++) o[k] = 0.f;

    tp_path<0, 0,0,0>(w[r][0],  xi, yi, o);
    tp_path<1, 0,1,1>(w[r][1],  xi, yi, o);
    tp_path<2, 0,2,2>(w[r][2],  xi, yi, o);
    tp_path<3, 1,0,1>(w[r][3],  xi, yi, o);
    tp_path<4, 1,1,0>(w[r][4],  xi, yi, o);
    tp_path<5, 1,1,2>(w[r][5],  xi, yi, o);
    tp_path<6, 1,2,1>(w[r][6],  xi, yi, o);
    tp_path<7, 2,0,2>(w[r][7],  xi, yi, o);
    tp_path<8, 2,1,1>(w[r][8],  xi, yi, o);
    tp_path<9, 2,2,0>(w[r][9],  xi, yi, o);
    tp_path<10,2,2,2>(w[r][10], xi, yi, o);

    float* o0 = op + r*288;
    vf4 s0 = { o[0], o[1], o[2], o[3] };
    vf4 s1 = { o[4], o[5], o[6], o[7] };
    __builtin_memcpy(o0,     &s0, 16);
    __builtin_memcpy(o0 + 4, &s1, 16);
    o0[8] = o[8];
  }
}

extern "C" void kernel_launch(void* const* d_in, const int* in_sizes, int n_in,
                              void* d_out, int out_size, void* d_ws, size_t ws_size,
                              hipStream_t stream)
{
  const float* x    = (const float*)d_in[0];
  const float* y    = (const float*)d_in[1];
  const float* dist = (const float*)d_in[2];
  const float* Wl   = (const float*)d_in[3];
  const float* bl   = (const float*)d_in[4];
  float* out = (float*)d_out;

  const int B = in_sizes[2] / 32;          // 131072 rows
  const int nblocks = (B / 64) * 2;        // 64 b's x 16 c's per block
  hipLaunchKernelGGL(e3_tp_kernel, dim3(nblocks), dim3(256), 0, stream,
                     x, y, dist, Wl, bl, out);
}

// Round 3
// 153.940 us; speedup vs baseline: 3.0529x; 3.0529x over previous
//
#include <hip/hip_runtime.h>

typedef float vf4 __attribute__((ext_vector_type(4)));

// ======================================================================
// Compile-time CG table (validated in rounds 1-2): real-SH CG build in
// fp64 via constexpr. Coefficients fold to literals; zeros DCE away.
// ======================================================================
namespace cgc {

struct FTab { double f[13]; };
constexpr FTab mkft(){ FTab t{}; t.f[0]=1.0; for(int i=1;i<13;i++) t.f[i]=t.f[i-1]*i; return t; }
constexpr FTab FTB = mkft();

constexpr double csqrt(double x){
  double g = x < 1.0 ? 1.0 : x;
  for(int i=0;i<40;i++) g = 0.5*(g + x/g);
  return g;
}

constexpr double cgcoef(int j1,int m1,int j2,int m2,int j3,int m3){
  if (m1+m2 != m3) return 0.0;
  double pref = csqrt((double)(2*j3+1) * FTB.f[j3+j1-j2] * FTB.f[j3-j1+j2]
                      * FTB.f[j1+j2-j3] / FTB.f[j1+j2+j3+1]);
  pref *= csqrt(FTB.f[j3+m3]*FTB.f[j3-m3]*FTB.f[j1-m1]*FTB.f[j1+m1]
                *FTB.f[j2-m2]*FTB.f[j2+m2]);
  double s = 0.0;
  for(int k=0;k<=j1+j2-j3;k++){
    int e1=j1+j2-j3-k, e2=j1-m1-k, e3=j2+m2-k, e4=j3-j2+m1+k, e5=j3-j1-m2+k;
    if (e1<0||e2<0||e3<0||e4<0||e5<0) continue;
    double prod = FTB.f[k]*FTB.f[e1]*FTB.f[e2]*FTB.f[e3]*FTB.f[e4]*FTB.f[e5];
    s += (k&1) ? (-1.0/prod) : (1.0/prod);
  }
  return pref*s;
}

struct Tab { double v[11][125]; };

constexpr Tab build(){
  Tab T{};
  constexpr int PL1[11]={0,0,0,1,1,1,1,2,2,2,2};
  constexpr int PL2[11]={0,1,2,0,1,1,2,0,1,2,2};
  constexpr int PL3[11]={0,1,2,1,0,2,1,2,1,0,2};
  constexpr int NOUT[3]={3,4,4};
  double qr[3][5][5]{}, qi[3][5][5]{};
  for(int l=0;l<3;l++){
    const double is2 = 0.70710678118654752440;
    for(int m=-l;m<0;m++){ qr[l][l+m][l-m]=is2; qi[l][l+m][l+m]=-is2; }
    qr[l][l][l]=1.0;
    for(int m=1;m<=l;m++){ double sg=(m&1)?-1.0:1.0; qr[l][l+m][l+m]=sg*is2; qi[l][l+m][l-m]=sg*is2; }
    if (l==1){ for(int a=0;a<5;a++)for(int b=0;b<5;b++){ double re=qr[1][a][b], im=qi[1][a][b]; qr[1][a][b]=im; qi[1][a][b]=-re; } }
    if (l==2){ for(int a=0;a<5;a++)for(int b=0;b<5;b++){ qr[2][a][b]=-qr[2][a][b]; qi[2][a][b]=-qi[2][a][b]; } }
  }
  for(int p=0;p<11;p++){
    int l1=PL1[p], l2=PL2[p], l3=PL3[p];
    int d1=2*l1+1, d2=2*l2+1, d3=2*l3+1;
    double cs[125]{};
    for(int i=0;i<d1;i++)for(int k=0;k<d2;k++)for(int m=0;m<d3;m++)
      cs[(i*d2+k)*d3+m] = cgcoef(l1,i-l1,l2,k-l2,l3,m-l3);
    double nrm2 = 0.0;
    for(int j=0;j<d1;j++)for(int lc=0;lc<d2;lc++)for(int n=0;n<d3;n++){
      double ar = 0.0;
      for(int i=0;i<d1;i++){
        double q1r=qr[l1][i][j], q1i=qi[l1][i][j];
        if (q1r==0.0 && q1i==0.0) continue;
        for(int k=0;k<d2;k++){
          double q2r=qr[l2][k][lc], q2i=qi[l2][k][lc];
          if (q2r==0.0 && q2i==0.0) continue;
          double abr=q1r*q2r-q1i*q2i, abi=q1r*q2i+q1i*q2r;
          for(int m=0;m<d3;m++){
            double c=cs[(i*d2+k)*d3+m];
            if (c==0.0) continue;
            double q3r=qr[l3][m][n], q3i=-qi[l3][m][n];   // conj(q3)
            ar += (abr*q3r - abi*q3i)*c;
          }
        }
      }
      T.v[p][(j*d2+lc)*d3+n] = ar;
      nrm2 += ar*ar;
    }
    double sc = csqrt((double)(2*l3+1)/(double)NOUT[l3]) / csqrt(nrm2);
    for(int e=0;e<d1*d2*d3;e++) T.v[p][e] *= sc;
  }
  return T;
}

constexpr Tab CGT = build();

} // namespace cgc

// ======================================================================
// Sparse per-path TP: coefficients are literals, zeros DCE'd.
// ======================================================================
template<int P,int L1,int L2,int L3>
__device__ __forceinline__ void tp_path(float wp, const float (&xi)[9],
                                        const float (&yi)[9], float (&o)[9])
{
  constexpr int D1=2*L1+1, D2=2*L2+1, D3=2*L3+1, O1=L1*L1, O2=L2*L2, O3=L3*L3;
  float z[D3];
#pragma unroll
  for(int k=0;k<D3;k++) z[k]=0.f;
#pragma unroll
  for(int i=0;i<D1;i++){
#pragma unroll
    for(int j=0;j<D2;j++){
      const float tt = xi[O1+i]*yi[O2+j];
#pragma unroll
      for(int k=0;k<D3;k++){
        const double cv = cgc::CGT.v[P][(i*D2+j)*D3+k];
        if (cv > 1e-12 || cv < -1e-12)
          z[k] = fmaf((float)cv, tt, z[k]);
      }
    }
  }
#pragma unroll
  for(int k=0;k<D3;k++) o[O3+k] = fmaf(wp, z[k], o[O3+k]);
}

// ======================================================================
// Main fused kernel. R1's proven shape: block = 32 b x 32 c, 256 thr
// (c = t&31, g = t>>5, R=4). W staged in TWO 16-f halves -> 24 KB LDS
// -> up to 6 blocks/CU. launch_bounds(256,4): 128-VGPR cap, no spill.
// ======================================================================
__global__ __launch_bounds__(256, 4) void e3_tp_kernel(
    const float* __restrict__ x, const float* __restrict__ y,
    const float* __restrict__ dist, const float* __restrict__ Wl,
    const float* __restrict__ bias, float* __restrict__ out)
{
  __shared__ float Ws[16*32*12];         // [f=16][c=32][12], 24 KB
  const vf4* Ws4 = (const vf4*)Ws;
  const int t = threadIdx.x;
  const int c = t & 31, g = t >> 5;
  const long b0 = (long)blockIdx.x*32 + g*4;

  // ---- fused linear: w[r][p] = bias[c][p] + sum_f dist[b0+r][f]*W[f][c][p]
  float w[4][11];
#pragma unroll
  for (int p = 0; p < 11; p++){
    const float bb = bias[c*11 + p];
#pragma unroll
    for (int r = 0; r < 4; r++) w[r][p] = bb;
  }

  const float* db = dist + b0*32;
  const vf4* wsrow = Ws4 + c*3;          // c*12 floats = 3 vf4

#pragma unroll 1
  for (int half = 0; half < 2; half++){
    if (half) __syncthreads();           // all waves done with previous half
    { // stage 16 f x 32 c x 11 p: 512 (f,cc) pairs, 2 per thread
#pragma unroll
      for (int q = 0; q < 2; q++){
        const int pr = t + q*256;
        const int f = pr >> 5, cc = pr & 31;
        const float* src = Wl + (half*16 + f)*352 + cc*11;
        float*       dst = Ws + f*384 + cc*12;
        vf4 a_, b_;
        __builtin_memcpy(&a_, src,   16);
        __builtin_memcpy(&b_, src+4, 16);
        *(vf4*)(dst)   = a_;             // byte f*1536+cc*48: 16B-aligned
        *(vf4*)(dst+4) = b_;
        dst[8] = src[8]; dst[9] = src[9]; dst[10] = src[10];
      }
    }
    __syncthreads();

    const float* dbh = db + half*16;
#pragma unroll 1
    for (int fq = 0; fq < 4; fq++){
      vf4 dd[4];
#pragma unroll
      for (int r = 0; r < 4; r++) dd[r] = *(const vf4*)(dbh + r*32 + fq*4);
#pragma unroll
      for (int ff = 0; ff < 4; ff++){
        const vf4* wr = wsrow + (fq*4 + ff)*96;   // f stride = 384 fl = 96 vf4
        vf4 wa = wr[0], wb2 = wr[1], wc2 = wr[2]; // 3x ds_read_b128
        const float wl[11] = {wa.x,wa.y,wa.z,wa.w, wb2.x,wb2.y,wb2.z,wb2.w,
                              wc2.x,wc2.y,wc2.z};
#pragma unroll
        for (int r = 0; r < 4; r++){
          const float dv = (ff==0) ? dd[r].x : (ff==1) ? dd[r].y
                         : (ff==2) ? dd[r].z : dd[r].w;
#pragma unroll
          for (int p = 0; p < 11; p++) w[r][p] = fmaf(dv, wl[p], w[r][p]);
        }
      }
    }
  }

  // ---- per-item tensor product ----
  const long ib = b0*32 + c;
  const float* xp = x + ib*9;
  const float* yp = y + ib*9;
  float* op = out + ib*9;

#pragma unroll
  for (int r = 0; r < 4; r++){
    const float* xr = xp + r*288;        // next b: +32*9 floats
    const float* yr = yp + r*288;
    float xi[9], yi[9], o[9];
    { vf4 a_, b_; __builtin_memcpy(&a_, xr, 16); __builtin_memcpy(&b_, xr+4, 16);
      xi[0]=a_.x; xi[1]=a_.y; xi[2]=a_.z; xi[3]=a_.w;
      xi[4]=b_.x; xi[5]=b_.y; xi[6]=b_.z; xi[7]=b_.w; xi[8]=xr[8]; }
    { vf4 a_, b_; __builtin_memcpy(&a_, yr, 16); __builtin_memcpy(&b_, yr+4, 16);
      yi[0]=a_.x; yi[1]=a_.y; yi[2]=a_.z; yi[3]=a_.w;
      yi[4]=b_.x; yi[5]=b_.y; yi[6]=b_.z; yi[7]=b_.w; yi[8]=yr[8]; }
#pragma unroll
    for (int k = 0; k < 9; k++) o[k] = 0.f;

    tp_path<0, 0,0,0>(w[r][0],  xi, yi, o);
    tp_path<1, 0,1,1>(w[r][1],  xi, yi, o);
    tp_path<2, 0,2,2>(w[r][2],  xi, yi, o);
    tp_path<3, 1,0,1>(w[r][3],  xi, yi, o);
    tp_path<4, 1,1,0>(w[r][4],  xi, yi, o);
    tp_path<5, 1,1,2>(w[r][5],  xi, yi, o);
    tp_path<6, 1,2,1>(w[r][6],  xi, yi, o);
    tp_path<7, 2,0,2>(w[r][7],  xi, yi, o);
    tp_path<8, 2,1,1>(w[r][8],  xi, yi, o);
    tp_path<9, 2,2,0>(w[r][9],  xi, yi, o);
    tp_path<10,2,2,2>(w[r][10], xi, yi, o);

    float* o0 = op + r*288;
    vf4 s0 = { o[0], o[1], o[2], o[3] };
    vf4 s1 = { o[4], o[5], o[6], o[7] };
    __builtin_memcpy(o0,     &s0, 16);
    __builtin_memcpy(o0 + 4, &s1, 16);
    o0[8] = o[8];
  }
}

extern "C" void kernel_launch(void* const* d_in, const int* in_sizes, int n_in,
                              void* d_out, int out_size, void* d_ws, size_t ws_size,
                              hipStream_t stream)
{
  const float* x    = (const float*)d_in[0];
  const float* y    = (const float*)d_in[1];
  const float* dist = (const float*)d_in[2];
  const float* Wl   = (const float*)d_in[3];
  const float* bl   = (const float*)d_in[4];
  float* out = (float*)d_out;

  const int B = in_sizes[2] / 32;        // 131072 rows
  const int nblocks = B / 32;            // 32 b's x 32 c's per block
  hipLaunchKernelGGL(e3_tp_kernel, dim3(nblocks), dim3(256), 0, stream,
                     x, y, dist, Wl, bl, out);
}